// Round 1
// baseline (203.479 us; speedup 1.0000x reference)
//
#include <hip/hip_runtime.h>

#define IMG_SIZE 256
#define NPIX (IMG_SIZE * IMG_SIZE)
#define KSEL 5
#define BS 8
#define LL 64
#define LUSED 63          // row l=63's top-k is discarded by the roll — never compute it
#define NTHREADS 256
#define SPLIT 4           // (fallback path) blocks per (b,l) row
#define CHUNK (NPIX / SPLIT)
#define PBINS 256         // R-channel bins for the counting sort
#define NROWS (BS * LUSED)

typedef unsigned long long ull;

// Branchless sorted-insert: loc[] ascending; bubble key in, evict the max.
__device__ __forceinline__ void sort_insert(ull loc[KSEL], ull key) {
    #pragma unroll
    for (int j = 0; j < KSEL; ++j) {
        const ull a = loc[j];
        const bool lt = key < a;
        loc[j] = lt ? key : a;
        key    = lt ? a : key;
    }
}

// Merge two ascending 5-lists, keep smallest 5 into a (fallback path only).
__device__ __forceinline__ void merge5(ull* a, const ull* b) {
    ull out[KSEL];
    int ia = 0, ib = 0;
    #pragma unroll
    for (int j = 0; j < KSEL; ++j) {
        const ull va = a[ia], vb = b[ib];
        const bool ta = va <= vb;
        out[j] = ta ? va : vb;
        ia += ta ? 1 : 0;
        ib += ta ? 0 : 1;
    }
    #pragma unroll
    for (int j = 0; j < KSEL; ++j) a[j] = out[j];
}

__device__ __forceinline__ ull
pix_key(float r0, float r1, float r2, float c0, float c1, float c2, int pix) {
    // Match numpy f32 exactly: no FMA contraction, ((d0^2+d1^2)+d2^2).
    float d0 = __fsub_rn(r0, c0);
    float d1 = __fsub_rn(r1, c1);
    float d2 = __fsub_rn(r2, c2);
    float s = __fadd_rn(__fadd_rn(__fmul_rn(d0, d0), __fmul_rn(d1, d1)), __fmul_rn(d2, d2));
    // s >= 0 -> uint bit order == float order; low bits = pixel index for
    // jax top_k's lower-index-first tie-break.
    return ((ull)__float_as_uint(s) << 32) | (unsigned int)pix;
}

// ---------------------------------------------------------------------------
// Fast path kernel 1: per-image counting sort by R channel.
// One block per image; LDS histogram -> Hillis-Steele scan -> scatter.
// Order within a bin is nondeterministic (atomics) but irrelevant: the top-5
// SET is determined by unique (s, idx) keys.
// ---------------------------------------------------------------------------
__global__ __launch_bounds__(1024)
void binsort_kernel(const float* __restrict__ imgs,
                    float4* __restrict__ sorted,
                    unsigned* __restrict__ bin_start) {
    const int img = blockIdx.x;
    const int t = threadIdx.x;
    __shared__ unsigned hist[PBINS];
    __shared__ unsigned scanb[PBINS];
    __shared__ unsigned cursor[PBINS];
    if (t < PBINS) hist[t] = 0u;
    __syncthreads();

    const float* base = imgs + (size_t)img * 3 * NPIX;
    #pragma unroll 4
    for (int it = 0; it < NPIX / 1024; ++it) {
        const int pix = it * 1024 + t;
        const float r = base[pix];
        const int bin = min(PBINS - 1, (int)(r * 256.0f));
        atomicAdd(&hist[bin], 1u);
    }
    __syncthreads();

    if (t < PBINS) scanb[t] = hist[t];
    __syncthreads();
    for (int st = 1; st < PBINS; st <<= 1) {
        unsigned v = 0u;
        if (t < PBINS && t >= st) v = scanb[t - st];
        __syncthreads();
        if (t < PBINS) scanb[t] += v;
        __syncthreads();
    }
    if (t < PBINS) {
        const unsigned s0 = scanb[t] - hist[t];       // exclusive prefix
        cursor[t] = s0;
        bin_start[img * (PBINS + 1) + t] = s0;
        if (t == PBINS - 1) bin_start[img * (PBINS + 1) + PBINS] = NPIX;
    }
    __syncthreads();

    float4* sp = sorted + (size_t)img * NPIX;
    #pragma unroll 2
    for (int it = 0; it < NPIX / 1024; ++it) {
        const int pix = it * 1024 + t;
        const float r  = base[pix];
        const float g  = base[NPIX + pix];
        const float bl = base[2 * NPIX + pix];
        const int bin = min(PBINS - 1, (int)(r * 256.0f));
        const unsigned pos = atomicAdd(&cursor[bin], 1u);
        sp[pos] = make_float4(r, g, bl, __uint_as_float((unsigned)pix));
    }
}

// ---------------------------------------------------------------------------
// Fast path kernel 2: one wave per (b,l) row. Expanding two-pointer scan over
// R-sorted bins with exact pruning. The wave keeps ONE shared top-5 (broadcast
// inserts), so the prune threshold is the exact running global 5th-best s.
// Prune is conservative: skip a side only if edge^2*0.99 - 1e-12 > s5, which
// dominates every f32 rounding in binning / key evaluation.
// ---------------------------------------------------------------------------
__global__ __launch_bounds__(NTHREADS)
void rows_kernel(const float* __restrict__ preds,
                 const float* __restrict__ imgs,
                 const float4* __restrict__ sorted,
                 const unsigned* __restrict__ bin_start,
                 float* __restrict__ bestd) {
    const int wave = threadIdx.x >> 6;
    const int lane = threadIdx.x & 63;
    const int row = blockIdx.x * 4 + wave;
    if (row >= NROWS) return;
    const int b = row / LUSED;
    const int l = row % LUSED;          // storage row; feeds loss row l+1

    // Scrambled pooled indexing (verified): flat i = l*bs + b.
    const int i = l * BS + b;
    const int pb = i >> 6;
    const int pl = i & 63;
    const float px = preds[pb * (LL * 8) + pl * 8 + 0];
    const float py = preds[pb * (LL * 8) + pl * 8 + 1];

    const float cx = __fsub_rn(__fmul_rn(px, 256.0f), 0.5f);
    const float cy = __fsub_rn(__fmul_rn(py, 256.0f), 0.5f);
    const int ix = (int)rintf(cx);
    const int iy = (int)rintf(cy);
    const bool valid = (ix >= 0) && (ix < IMG_SIZE) && (iy >= 0) && (iy < IMG_SIZE);
    const int ixc = min(max(ix, 0), IMG_SIZE - 1);
    const int iyc = min(max(iy, 0), IMG_SIZE - 1);
    const float vmul = valid ? 1.0f : 0.0f;

    const float* imgb = imgs + (size_t)b * 3 * NPIX;
    const float c0 = imgb[0 * NPIX + iyc * IMG_SIZE + ixc] * vmul;
    const float c1 = imgb[1 * NPIX + iyc * IMG_SIZE + ixc] * vmul;
    const float c2 = imgb[2 * NPIX + iyc * IMG_SIZE + ixc] * vmul;

    const unsigned* bst = bin_start + b * (PBINS + 1);
    const float4* sp = sorted + (size_t)b * NPIX;

    ull loc[KSEL];
    #pragma unroll
    for (int j = 0; j < KSEL; ++j) loc[j] = 0xFFFFFFFFFFFFFFFFULL;

    // Evaluate one bin; inserts are wave-uniform broadcasts so every lane's
    // loc[] stays identical (exact shared top-5, exact threshold).
    auto process = [&](int k) {
        const int start = (int)bst[k];
        const int cnt = (int)bst[k + 1] - start;
        for (int o = lane; o < ((cnt + 63) & ~63); o += 64) {
            const bool act = o < cnt;
            const int tt = start + (act ? o : 0);
            const float4 v = sp[tt];
            ull key = 0xFFFFFFFFFFFFFFFFULL;
            if (act) key = pix_key(v.x, v.y, v.z, c0, c1, c2, (int)__float_as_uint(v.w));
            ull mask = __ballot(key < loc[KSEL - 1]);
            while (mask) {
                const int ln = __ffsll(mask) - 1;
                mask &= mask - 1;
                const ull kk = __shfl(key, ln);   // broadcast; all lanes insert
                sort_insert(loc, kk);
            }
        }
    };

    const int bc = min(PBINS - 1, max(0, (int)(c0 * 256.0f)));
    process(bc);
    int lo = bc, hi = bc;
    bool openL = bc > 0;
    bool openR = bc < PBINS - 1;
    while (openL || openR) {
        const unsigned thr = (unsigned)(loc[KSEL - 1] >> 32);  // f32 bits of s5 (or FFFF.. sentinel)
        float eL = 0.0f, eR = 0.0f;
        if (openL) {
            eL = __fsub_rn(c0, (float)lo * (1.0f / 256.0f));   // edge of bin lo-1
            const float q = fmaxf(eL * eL * 0.99f - 1e-12f, 0.0f);
            if (__float_as_uint(q) > thr) openL = false;       // u32 cmp == f32 cmp (both >=0); sentinel never pruned
        }
        if (openR) {
            eR = __fsub_rn((float)(hi + 1) * (1.0f / 256.0f), c0);
            const float q = fmaxf(eR * eR * 0.99f - 1e-12f, 0.0f);
            if (__float_as_uint(q) > thr) openR = false;
        }
        if (!openL && !openR) break;
        const bool goL = openL && (!openR || eL <= eR);        // nearer side first -> tight threshold early
        if (goL) { lo -= 1; process(lo); if (lo == 0) openL = false; }
        else     { hi += 1; process(hi); if (hi == PBINS - 1) openR = false; }
    }

    // All lanes hold the identical global top-5. Lane 0 computes the loss
    // element for loss row l+1 (same f32 ops as the verified finalize).
    if (lane == 0) {
        const float pxl = preds[b * (LL * 8) + (l + 1) * 8 + 0];
        const float pyl = preds[b * (LL * 8) + (l + 1) * 8 + 1];
        float best = 3.4028235e38f;
        #pragma unroll
        for (int k = 0; k < KSEL; ++k) {
            const int ixk = (int)(loc[k] & 0xFFFFFFFFULL);
            const float tx = (float)(ixk & 255) * (1.0f / 256.0f);
            const float ty = (float)(ixk >> 8) * (1.0f / 256.0f);
            const float dx = __fsub_rn(pxl, tx);
            const float dy = __fsub_rn(pyl, ty);
            const float dist = __fadd_rn(__fmul_rn(dx, dx), __fmul_rn(dy, dy));
            best = dist < best ? dist : best;
        }
        bestd[row] = best;
    }
}

// Fast path kernel 3: deterministic sum (bitwise-identical tree to the
// verified finalize tail).
__global__ __launch_bounds__(NTHREADS)
void sum_kernel(const float* __restrict__ bestd, float* __restrict__ out) {
    const int t = threadIdx.x;
    float acc = 0.0f;
    for (int p = t; p < NROWS; p += NTHREADS) acc += bestd[p];
    __shared__ float red[NTHREADS];
    red[t] = acc;
    __syncthreads();
    for (int s = NTHREADS / 2; s > 0; s >>= 1) {
        if (t < s) red[t] += red[t + s];
        __syncthreads();
    }
    if (t == 0) out[0] = red[0] / (float)(BS * (LL - 1));
}

// ---------------------------------------------------------------------------
// Fallback path (verified, 100.4 us): brute-force scan + merge. Used only if
// the workspace is too small for the sorted-color buffer.
// ---------------------------------------------------------------------------
__global__ __launch_bounds__(NTHREADS)
void topk_kernel(const float* __restrict__ preds,
                 const float* __restrict__ imgs,
                 ull* __restrict__ keys_out) {
    const int blk = blockIdx.x;
    const int split = blk & (SPLIT - 1);
    const int row = blk / SPLIT;
    const int b = row / LUSED;
    const int l = row % LUSED;
    const int bid = b * LL + l;
    const int t = threadIdx.x;

    const int i = l * BS + b;
    const int pb = i >> 6;
    const int pl = i & 63;
    const float px = preds[pb * (LL * 8) + pl * 8 + 0];
    const float py = preds[pb * (LL * 8) + pl * 8 + 1];

    const float cx = __fsub_rn(__fmul_rn(px, 256.0f), 0.5f);
    const float cy = __fsub_rn(__fmul_rn(py, 256.0f), 0.5f);
    const int ix = (int)rintf(cx);
    const int iy = (int)rintf(cy);
    const bool valid = (ix >= 0) && (ix < IMG_SIZE) && (iy >= 0) && (iy < IMG_SIZE);
    const int ixc = min(max(ix, 0), IMG_SIZE - 1);
    const int iyc = min(max(iy, 0), IMG_SIZE - 1);
    const float vmul = valid ? 1.0f : 0.0f;

    const float* imgb = imgs + (size_t)b * 3 * NPIX;
    const float c0 = imgb[0 * NPIX + iyc * IMG_SIZE + ixc] * vmul;
    const float c1 = imgb[1 * NPIX + iyc * IMG_SIZE + ixc] * vmul;
    const float c2 = imgb[2 * NPIX + iyc * IMG_SIZE + ixc] * vmul;

    const float4* p0 = (const float4*)(imgb + 0 * NPIX);
    const float4* p1 = (const float4*)(imgb + 1 * NPIX);
    const float4* p2 = (const float4*)(imgb + 2 * NPIX);

    ull loc[KSEL];
    #pragma unroll
    for (int j = 0; j < KSEL; ++j) loc[j] = 0xFFFFFFFFFFFFFFFFULL;

    const int v0 = split * (CHUNK / 4);
    #pragma unroll 2
    for (int it = 0; it < CHUNK / 4 / NTHREADS; ++it) {
        const int v = v0 + it * NTHREADS + t;
        float4 r0 = p0[v];
        float4 r1 = p1[v];
        float4 r2 = p2[v];
        const int base = v * 4;
        sort_insert(loc, pix_key(r0.x, r1.x, r2.x, c0, c1, c2, base + 0));
        sort_insert(loc, pix_key(r0.y, r1.y, r2.y, c0, c1, c2, base + 1));
        sort_insert(loc, pix_key(r0.z, r1.z, r2.z, c0, c1, c2, base + 2));
        sort_insert(loc, pix_key(r0.w, r1.w, r2.w, c0, c1, c2, base + 3));
    }

    __shared__ ull sk[NTHREADS * KSEL];
    #pragma unroll
    for (int j = 0; j < KSEL; ++j) sk[t * KSEL + j] = loc[j];
    __syncthreads();

    for (int s = NTHREADS / 2; s > 0; s >>= 1) {
        if (t < s) {
            ull a[KSEL], bb[KSEL];
            #pragma unroll
            for (int j = 0; j < KSEL; ++j) { a[j] = sk[t * KSEL + j]; bb[j] = sk[(t + s) * KSEL + j]; }
            merge5(a, bb);
            #pragma unroll
            for (int j = 0; j < KSEL; ++j) sk[t * KSEL + j] = a[j];
        }
        __syncthreads();
    }

    if (t < KSEL) {
        keys_out[((size_t)bid * SPLIT + split) * KSEL + t] = sk[t];
    }
}

__global__ __launch_bounds__(NTHREADS)
void finalize_kernel(const float* __restrict__ preds,
                     const ull* __restrict__ keys,
                     float* __restrict__ out) {
    const int t = threadIdx.x;
    float acc = 0.0f;

    for (int p = t; p < BS * LUSED; p += NTHREADS) {
        const int b = p / LUSED;
        const int l = p % LUSED + 1;
        const float px = preds[b * (LL * 8) + l * 8 + 0];
        const float py = preds[b * (LL * 8) + l * 8 + 1];

        const int srow = b * LL + (l - 1);
        ull loc[KSEL];
        #pragma unroll
        for (int j = 0; j < KSEL; ++j) loc[j] = 0xFFFFFFFFFFFFFFFFULL;
        #pragma unroll
        for (int s = 0; s < SPLIT; ++s) {
            #pragma unroll
            for (int k = 0; k < KSEL; ++k) {
                sort_insert(loc, keys[((size_t)srow * SPLIT + s) * KSEL + k]);
            }
        }

        float best = 3.4028235e38f;
        #pragma unroll
        for (int k = 0; k < KSEL; ++k) {
            const int ixk = (int)(loc[k] & 0xFFFFFFFFULL);
            const float tx = (float)(ixk & 255) * (1.0f / 256.0f);
            const float ty = (float)(ixk >> 8) * (1.0f / 256.0f);
            const float dx = __fsub_rn(px, tx);
            const float dy = __fsub_rn(py, ty);
            const float dist = __fadd_rn(__fmul_rn(dx, dx), __fmul_rn(dy, dy));
            best = dist < best ? dist : best;
        }
        acc += best;
    }

    __shared__ float red[NTHREADS];
    red[t] = acc;
    __syncthreads();
    for (int s = NTHREADS / 2; s > 0; s >>= 1) {
        if (t < s) red[t] += red[t + s];
        __syncthreads();
    }
    if (t == 0) {
        out[0] = red[0] / (float)(BS * (LL - 1));
    }
}

extern "C" void kernel_launch(void* const* d_in, const int* in_sizes, int n_in,
                              void* d_out, int out_size, void* d_ws, size_t ws_size,
                              hipStream_t stream) {
    const float* preds = (const float*)d_in[0];   // (8, 64, 8) f32
    const float* imgs  = (const float*)d_in[1];   // (8, 3, 256, 256) f32
    float* out = (float*)d_out;                   // scalar f32

    const size_t SORT_BYTES   = (size_t)BS * NPIX * sizeof(float4);           // 8 MB
    const size_t BSTART_BYTES = ((size_t)BS * (PBINS + 1) * sizeof(unsigned) + 15) & ~(size_t)15;
    const size_t BESTD_BYTES  = (size_t)NROWS * sizeof(float);

    if (ws_size >= SORT_BYTES + BSTART_BYTES + BESTD_BYTES) {
        float4*   sorted    = (float4*)d_ws;
        unsigned* bin_start = (unsigned*)((char*)d_ws + SORT_BYTES);
        float*    bestd     = (float*)((char*)d_ws + SORT_BYTES + BSTART_BYTES);
        binsort_kernel<<<dim3(BS), dim3(1024), 0, stream>>>(imgs, sorted, bin_start);
        rows_kernel<<<dim3((NROWS + 3) / 4), dim3(NTHREADS), 0, stream>>>(preds, imgs, sorted, bin_start, bestd);
        sum_kernel<<<dim3(1), dim3(NTHREADS), 0, stream>>>(bestd, out);
    } else {
        // Fallback: verified brute-force path (needs only 80 KB workspace).
        ull* keys = (ull*)d_ws;
        topk_kernel<<<dim3(BS * LUSED * SPLIT), dim3(NTHREADS), 0, stream>>>(preds, imgs, keys);
        finalize_kernel<<<dim3(1), dim3(NTHREADS), 0, stream>>>(preds, keys, out);
    }
}

// Round 2
// 123.356 us; speedup vs baseline: 1.6495x; 1.6495x over previous
//
#include <hip/hip_runtime.h>

#define IMG_SIZE 256
#define NPIX (IMG_SIZE * IMG_SIZE)
#define KSEL 5
#define BS 8
#define LL 64
#define LUSED 63          // row l=63's top-k is discarded by the roll — never compute it
#define NTHREADS 256
#define SPLIT 4           // (fallback path) blocks per (b,l) row
#define CHUNK (NPIX / SPLIT)
#define PBINS 256         // R-channel bins for the counting sort
#define NROWS (BS * LUSED)
#define NBPI 64           // sort blocks per image (1024 pixels each)

typedef unsigned long long ull;

// Branchless sorted-insert: loc[] ascending; bubble key in, evict the max.
__device__ __forceinline__ void sort_insert(ull loc[KSEL], ull key) {
    #pragma unroll
    for (int j = 0; j < KSEL; ++j) {
        const ull a = loc[j];
        const bool lt = key < a;
        loc[j] = lt ? key : a;
        key    = lt ? a : key;
    }
}

// Merge two ascending 5-lists, keep smallest 5 into a (fallback path only).
__device__ __forceinline__ void merge5(ull* a, const ull* b) {
    ull out[KSEL];
    int ia = 0, ib = 0;
    #pragma unroll
    for (int j = 0; j < KSEL; ++j) {
        const ull va = a[ia], vb = b[ib];
        const bool ta = va <= vb;
        out[j] = ta ? va : vb;
        ia += ta ? 1 : 0;
        ib += ta ? 0 : 1;
    }
    #pragma unroll
    for (int j = 0; j < KSEL; ++j) a[j] = out[j];
}

__device__ __forceinline__ ull
pix_key(float r0, float r1, float r2, float c0, float c1, float c2, int pix) {
    // Match numpy f32 exactly: no FMA contraction, ((d0^2+d1^2)+d2^2).
    float d0 = __fsub_rn(r0, c0);
    float d1 = __fsub_rn(r1, c1);
    float d2 = __fsub_rn(r2, c2);
    float s = __fadd_rn(__fadd_rn(__fmul_rn(d0, d0), __fmul_rn(d1, d1)), __fmul_rn(d2, d2));
    // s >= 0 -> uint bit order == float order; low bits = pixel index for
    // jax top_k's lower-index-first tie-break.
    return ((ull)__float_as_uint(s) << 32) | (unsigned int)pix;
}

// Binning formula — must be IDENTICAL in hist/scatter (and consistent with the
// bin-edge arithmetic in rows_kernel's prune, which it is: pixels in bin k have
// r within ~1ulp of [k/256,(k+1)/256), dominated by the 0.99/1e-12 slack).
__device__ __forceinline__ int rbin(float r) {
    return min(PBINS - 1, (int)(r * 256.0f));
}

// ---------------------------------------------------------------------------
// Fast path kernel 1: per-block histograms. 64 blocks/image, 1024 pixels each
// (one float4 of R per thread). Plain stores, no global atomics, no init.
// ---------------------------------------------------------------------------
__global__ __launch_bounds__(NTHREADS)
void hist_kernel(const float* __restrict__ imgs,
                 unsigned* __restrict__ blockhist) {
    const int blk = blockIdx.x;           // 0 .. BS*NBPI-1
    const int img = blk >> 6;
    const int sub = blk & (NBPI - 1);
    const int t = threadIdx.x;
    __shared__ unsigned h[PBINS];
    h[t] = 0u;
    __syncthreads();
    const float4* rp = (const float4*)(imgs + (size_t)img * 3 * NPIX);
    const float4 r = rp[sub * NTHREADS + t];
    atomicAdd(&h[rbin(r.x)], 1u);
    atomicAdd(&h[rbin(r.y)], 1u);
    atomicAdd(&h[rbin(r.z)], 1u);
    atomicAdd(&h[rbin(r.w)], 1u);
    __syncthreads();
    blockhist[blk * PBINS + t] = h[t];
}

// ---------------------------------------------------------------------------
// Fast path kernel 2: per-image scan. One block/image, thread t = bin t.
// total -> exclusive bin_start -> per-sort-block reservation bases (cur_base).
// Fully deterministic; no atomics, no memset.
// ---------------------------------------------------------------------------
__global__ __launch_bounds__(NTHREADS)
void scan_kernel(const unsigned* __restrict__ blockhist,
                 unsigned* __restrict__ bin_start,
                 unsigned* __restrict__ cur_base) {
    const int img = blockIdx.x;
    const int t = threadIdx.x;
    unsigned total = 0u;
    #pragma unroll 4
    for (int blk = 0; blk < NBPI; ++blk)
        total += blockhist[(img * NBPI + blk) * PBINS + t];

    __shared__ unsigned sc[PBINS];
    sc[t] = total;
    __syncthreads();
    for (int st = 1; st < PBINS; st <<= 1) {
        const unsigned v = (t >= st) ? sc[t - st] : 0u;
        __syncthreads();
        sc[t] += v;
        __syncthreads();
    }
    const unsigned start = sc[t] - total;     // exclusive prefix over bins
    bin_start[img * (PBINS + 1) + t] = start;
    if (t == 0) bin_start[img * (PBINS + 1) + PBINS] = NPIX;

    unsigned run = start;
    #pragma unroll 4
    for (int blk = 0; blk < NBPI; ++blk) {
        cur_base[(img * NBPI + blk) * PBINS + t] = run;
        run += blockhist[(img * NBPI + blk) * PBINS + t];
    }
}

// ---------------------------------------------------------------------------
// Fast path kernel 3: parallel scatter. Each block owns a private reservation
// per bin (cur_base row) -> LDS cursor -> conflict-free global positions.
// Within-bin order nondeterministic (irrelevant: top-5 SET is determined by
// unique (s,idx) keys; prune bound is order-independent).
// ---------------------------------------------------------------------------
__global__ __launch_bounds__(NTHREADS)
void scatter_kernel(const float* __restrict__ imgs,
                    const unsigned* __restrict__ cur_base,
                    float4* __restrict__ sorted) {
    const int blk = blockIdx.x;
    const int img = blk >> 6;
    const int sub = blk & (NBPI - 1);
    const int t = threadIdx.x;
    __shared__ unsigned cur[PBINS];
    cur[t] = cur_base[blk * PBINS + t];
    __syncthreads();

    const float* base = imgs + (size_t)img * 3 * NPIX;
    const int i4 = sub * NTHREADS + t;
    const float4 r  = ((const float4*)(base))[i4];
    const float4 g  = ((const float4*)(base + NPIX))[i4];
    const float4 bl = ((const float4*)(base + 2 * NPIX))[i4];
    float4* sp = sorted + (size_t)img * NPIX;
    const unsigned pix0 = (unsigned)(i4 * 4);

    unsigned p;
    p = atomicAdd(&cur[rbin(r.x)], 1u); sp[p] = make_float4(r.x, g.x, bl.x, __uint_as_float(pix0 + 0u));
    p = atomicAdd(&cur[rbin(r.y)], 1u); sp[p] = make_float4(r.y, g.y, bl.y, __uint_as_float(pix0 + 1u));
    p = atomicAdd(&cur[rbin(r.z)], 1u); sp[p] = make_float4(r.z, g.z, bl.z, __uint_as_float(pix0 + 2u));
    p = atomicAdd(&cur[rbin(r.w)], 1u); sp[p] = make_float4(r.w, g.w, bl.w, __uint_as_float(pix0 + 3u));
}

// ---------------------------------------------------------------------------
// Fast path kernel 4: one wave per (b,l) row. Expanding two-pointer scan over
// R-sorted bins with exact pruning. The wave keeps ONE shared top-5 (broadcast
// inserts), so the prune threshold is the exact running global 5th-best s.
// Prune is conservative: skip a side only if edge^2*0.99 - 1e-12 > s5, which
// dominates every f32 rounding in binning / key evaluation.
// (Harness-verified last round: passed, absmax 0.0.)
// ---------------------------------------------------------------------------
__global__ __launch_bounds__(NTHREADS)
void rows_kernel(const float* __restrict__ preds,
                 const float* __restrict__ imgs,
                 const float4* __restrict__ sorted,
                 const unsigned* __restrict__ bin_start,
                 float* __restrict__ bestd) {
    const int wave = threadIdx.x >> 6;
    const int lane = threadIdx.x & 63;
    const int row = blockIdx.x * 4 + wave;
    if (row >= NROWS) return;
    const int b = row / LUSED;
    const int l = row % LUSED;          // storage row; feeds loss row l+1

    // Scrambled pooled indexing (verified): flat i = l*bs + b.
    const int i = l * BS + b;
    const int pb = i >> 6;
    const int pl = i & 63;
    const float px = preds[pb * (LL * 8) + pl * 8 + 0];
    const float py = preds[pb * (LL * 8) + pl * 8 + 1];

    const float cx = __fsub_rn(__fmul_rn(px, 256.0f), 0.5f);
    const float cy = __fsub_rn(__fmul_rn(py, 256.0f), 0.5f);
    const int ix = (int)rintf(cx);
    const int iy = (int)rintf(cy);
    const bool valid = (ix >= 0) && (ix < IMG_SIZE) && (iy >= 0) && (iy < IMG_SIZE);
    const int ixc = min(max(ix, 0), IMG_SIZE - 1);
    const int iyc = min(max(iy, 0), IMG_SIZE - 1);
    const float vmul = valid ? 1.0f : 0.0f;

    const float* imgb = imgs + (size_t)b * 3 * NPIX;
    const float c0 = imgb[0 * NPIX + iyc * IMG_SIZE + ixc] * vmul;
    const float c1 = imgb[1 * NPIX + iyc * IMG_SIZE + ixc] * vmul;
    const float c2 = imgb[2 * NPIX + iyc * IMG_SIZE + ixc] * vmul;

    const unsigned* bst = bin_start + b * (PBINS + 1);
    const float4* sp = sorted + (size_t)b * NPIX;

    ull loc[KSEL];
    #pragma unroll
    for (int j = 0; j < KSEL; ++j) loc[j] = 0xFFFFFFFFFFFFFFFFULL;

    // Evaluate one bin; inserts are wave-uniform broadcasts so every lane's
    // loc[] stays identical (exact shared top-5, exact threshold).
    auto process = [&](int k) {
        const int start = (int)bst[k];
        const int cnt = (int)bst[k + 1] - start;
        for (int o = lane; o < ((cnt + 63) & ~63); o += 64) {
            const bool act = o < cnt;
            const int tt = start + (act ? o : 0);
            const float4 v = sp[tt];
            ull key = 0xFFFFFFFFFFFFFFFFULL;
            if (act) key = pix_key(v.x, v.y, v.z, c0, c1, c2, (int)__float_as_uint(v.w));
            ull mask = __ballot(key < loc[KSEL - 1]);
            while (mask) {
                const int ln = __ffsll(mask) - 1;
                mask &= mask - 1;
                const ull kk = __shfl(key, ln);   // broadcast; all lanes insert
                sort_insert(loc, kk);
            }
        }
    };

    const int bc = min(PBINS - 1, max(0, (int)(c0 * 256.0f)));
    process(bc);
    int lo = bc, hi = bc;
    bool openL = bc > 0;
    bool openR = bc < PBINS - 1;
    while (openL || openR) {
        const unsigned thr = (unsigned)(loc[KSEL - 1] >> 32);  // f32 bits of s5 (or FFFF.. sentinel)
        float eL = 0.0f, eR = 0.0f;
        if (openL) {
            eL = __fsub_rn(c0, (float)lo * (1.0f / 256.0f));   // edge of bin lo-1
            const float q = fmaxf(eL * eL * 0.99f - 1e-12f, 0.0f);
            if (__float_as_uint(q) > thr) openL = false;       // u32 cmp == f32 cmp (both >=0); sentinel never pruned
        }
        if (openR) {
            eR = __fsub_rn((float)(hi + 1) * (1.0f / 256.0f), c0);
            const float q = fmaxf(eR * eR * 0.99f - 1e-12f, 0.0f);
            if (__float_as_uint(q) > thr) openR = false;
        }
        if (!openL && !openR) break;
        const bool goL = openL && (!openR || eL <= eR);        // nearer side first -> tight threshold early
        if (goL) { lo -= 1; process(lo); if (lo == 0) openL = false; }
        else     { hi += 1; process(hi); if (hi == PBINS - 1) openR = false; }
    }

    // All lanes hold the identical global top-5. Lane 0 computes the loss
    // element for loss row l+1 (same f32 ops as the verified finalize).
    if (lane == 0) {
        const float pxl = preds[b * (LL * 8) + (l + 1) * 8 + 0];
        const float pyl = preds[b * (LL * 8) + (l + 1) * 8 + 1];
        float best = 3.4028235e38f;
        #pragma unroll
        for (int k = 0; k < KSEL; ++k) {
            const int ixk = (int)(loc[k] & 0xFFFFFFFFULL);
            const float tx = (float)(ixk & 255) * (1.0f / 256.0f);
            const float ty = (float)(ixk >> 8) * (1.0f / 256.0f);
            const float dx = __fsub_rn(pxl, tx);
            const float dy = __fsub_rn(pyl, ty);
            const float dist = __fadd_rn(__fmul_rn(dx, dx), __fmul_rn(dy, dy));
            best = dist < best ? dist : best;
        }
        bestd[row] = best;
    }
}

// Fast path kernel 5: deterministic sum (bitwise-identical tree to the
// verified finalize tail).
__global__ __launch_bounds__(NTHREADS)
void sum_kernel(const float* __restrict__ bestd, float* __restrict__ out) {
    const int t = threadIdx.x;
    float acc = 0.0f;
    for (int p = t; p < NROWS; p += NTHREADS) acc += bestd[p];
    __shared__ float red[NTHREADS];
    red[t] = acc;
    __syncthreads();
    for (int s = NTHREADS / 2; s > 0; s >>= 1) {
        if (t < s) red[t] += red[t + s];
        __syncthreads();
    }
    if (t == 0) out[0] = red[0] / (float)(BS * (LL - 1));
}

// ---------------------------------------------------------------------------
// Fallback path (verified, 100.4 us): brute-force scan + merge. Used only if
// the workspace is too small for the sort buffers.
// ---------------------------------------------------------------------------
__global__ __launch_bounds__(NTHREADS)
void topk_kernel(const float* __restrict__ preds,
                 const float* __restrict__ imgs,
                 ull* __restrict__ keys_out) {
    const int blk = blockIdx.x;
    const int split = blk & (SPLIT - 1);
    const int row = blk / SPLIT;
    const int b = row / LUSED;
    const int l = row % LUSED;
    const int bid = b * LL + l;
    const int t = threadIdx.x;

    const int i = l * BS + b;
    const int pb = i >> 6;
    const int pl = i & 63;
    const float px = preds[pb * (LL * 8) + pl * 8 + 0];
    const float py = preds[pb * (LL * 8) + pl * 8 + 1];

    const float cx = __fsub_rn(__fmul_rn(px, 256.0f), 0.5f);
    const float cy = __fsub_rn(__fmul_rn(py, 256.0f), 0.5f);
    const int ix = (int)rintf(cx);
    const int iy = (int)rintf(cy);
    const bool valid = (ix >= 0) && (ix < IMG_SIZE) && (iy >= 0) && (iy < IMG_SIZE);
    const int ixc = min(max(ix, 0), IMG_SIZE - 1);
    const int iyc = min(max(iy, 0), IMG_SIZE - 1);
    const float vmul = valid ? 1.0f : 0.0f;

    const float* imgb = imgs + (size_t)b * 3 * NPIX;
    const float c0 = imgb[0 * NPIX + iyc * IMG_SIZE + ixc] * vmul;
    const float c1 = imgb[1 * NPIX + iyc * IMG_SIZE + ixc] * vmul;
    const float c2 = imgb[2 * NPIX + iyc * IMG_SIZE + ixc] * vmul;

    const float4* p0 = (const float4*)(imgb + 0 * NPIX);
    const float4* p1 = (const float4*)(imgb + 1 * NPIX);
    const float4* p2 = (const float4*)(imgb + 2 * NPIX);

    ull loc[KSEL];
    #pragma unroll
    for (int j = 0; j < KSEL; ++j) loc[j] = 0xFFFFFFFFFFFFFFFFULL;

    const int v0 = split * (CHUNK / 4);
    #pragma unroll 2
    for (int it = 0; it < CHUNK / 4 / NTHREADS; ++it) {
        const int v = v0 + it * NTHREADS + t;
        float4 r0 = p0[v];
        float4 r1 = p1[v];
        float4 r2 = p2[v];
        const int base = v * 4;
        sort_insert(loc, pix_key(r0.x, r1.x, r2.x, c0, c1, c2, base + 0));
        sort_insert(loc, pix_key(r0.y, r1.y, r2.y, c0, c1, c2, base + 1));
        sort_insert(loc, pix_key(r0.z, r1.z, r2.z, c0, c1, c2, base + 2));
        sort_insert(loc, pix_key(r0.w, r1.w, r2.w, c0, c1, c2, base + 3));
    }

    __shared__ ull sk[NTHREADS * KSEL];
    #pragma unroll
    for (int j = 0; j < KSEL; ++j) sk[t * KSEL + j] = loc[j];
    __syncthreads();

    for (int s = NTHREADS / 2; s > 0; s >>= 1) {
        if (t < s) {
            ull a[KSEL], bb[KSEL];
            #pragma unroll
            for (int j = 0; j < KSEL; ++j) { a[j] = sk[t * KSEL + j]; bb[j] = sk[(t + s) * KSEL + j]; }
            merge5(a, bb);
            #pragma unroll
            for (int j = 0; j < KSEL; ++j) sk[t * KSEL + j] = a[j];
        }
        __syncthreads();
    }

    if (t < KSEL) {
        keys_out[((size_t)bid * SPLIT + split) * KSEL + t] = sk[t];
    }
}

__global__ __launch_bounds__(NTHREADS)
void finalize_kernel(const float* __restrict__ preds,
                     const ull* __restrict__ keys,
                     float* __restrict__ out) {
    const int t = threadIdx.x;
    float acc = 0.0f;

    for (int p = t; p < BS * LUSED; p += NTHREADS) {
        const int b = p / LUSED;
        const int l = p % LUSED + 1;
        const float px = preds[b * (LL * 8) + l * 8 + 0];
        const float py = preds[b * (LL * 8) + l * 8 + 1];

        const int srow = b * LL + (l - 1);
        ull loc[KSEL];
        #pragma unroll
        for (int j = 0; j < KSEL; ++j) loc[j] = 0xFFFFFFFFFFFFFFFFULL;
        #pragma unroll
        for (int s = 0; s < SPLIT; ++s) {
            #pragma unroll
            for (int k = 0; k < KSEL; ++k) {
                sort_insert(loc, keys[((size_t)srow * SPLIT + s) * KSEL + k]);
            }
        }

        float best = 3.4028235e38f;
        #pragma unroll
        for (int k = 0; k < KSEL; ++k) {
            const int ixk = (int)(loc[k] & 0xFFFFFFFFULL);
            const float tx = (float)(ixk & 255) * (1.0f / 256.0f);
            const float ty = (float)(ixk >> 8) * (1.0f / 256.0f);
            const float dx = __fsub_rn(px, tx);
            const float dy = __fsub_rn(py, ty);
            const float dist = __fadd_rn(__fmul_rn(dx, dx), __fmul_rn(dy, dy));
            best = dist < best ? dist : best;
        }
        acc += best;
    }

    __shared__ float red[NTHREADS];
    red[t] = acc;
    __syncthreads();
    for (int s = NTHREADS / 2; s > 0; s >>= 1) {
        if (t < s) red[t] += red[t + s];
        __syncthreads();
    }
    if (t == 0) {
        out[0] = red[0] / (float)(BS * (LL - 1));
    }
}

extern "C" void kernel_launch(void* const* d_in, const int* in_sizes, int n_in,
                              void* d_out, int out_size, void* d_ws, size_t ws_size,
                              hipStream_t stream) {
    const float* preds = (const float*)d_in[0];   // (8, 64, 8) f32
    const float* imgs  = (const float*)d_in[1];   // (8, 3, 256, 256) f32
    float* out = (float*)d_out;                   // scalar f32

    const size_t SORT_BYTES   = (size_t)BS * NPIX * sizeof(float4);                       // 8 MB
    const size_t BSTART_BYTES = ((size_t)BS * (PBINS + 1) * sizeof(unsigned) + 15) & ~(size_t)15;
    const size_t BESTD_BYTES  = ((size_t)NROWS * sizeof(float) + 15) & ~(size_t)15;
    const size_t BHIST_BYTES  = (size_t)BS * NBPI * PBINS * sizeof(unsigned);             // 512 KB
    const size_t CBASE_BYTES  = (size_t)BS * NBPI * PBINS * sizeof(unsigned);             // 512 KB
    const size_t TOTAL = SORT_BYTES + BSTART_BYTES + BESTD_BYTES + BHIST_BYTES + CBASE_BYTES;

    if (ws_size >= TOTAL) {
        char* p = (char*)d_ws;
        float4*   sorted    = (float4*)p;              p += SORT_BYTES;
        unsigned* bin_start = (unsigned*)p;            p += BSTART_BYTES;
        float*    bestd     = (float*)p;               p += BESTD_BYTES;
        unsigned* blockhist = (unsigned*)p;            p += BHIST_BYTES;
        unsigned* cur_base  = (unsigned*)p;

        hist_kernel   <<<dim3(BS * NBPI), dim3(NTHREADS), 0, stream>>>(imgs, blockhist);
        scan_kernel   <<<dim3(BS),        dim3(NTHREADS), 0, stream>>>(blockhist, bin_start, cur_base);
        scatter_kernel<<<dim3(BS * NBPI), dim3(NTHREADS), 0, stream>>>(imgs, cur_base, sorted);
        rows_kernel   <<<dim3((NROWS + 3) / 4), dim3(NTHREADS), 0, stream>>>(preds, imgs, sorted, bin_start, bestd);
        sum_kernel    <<<dim3(1),         dim3(NTHREADS), 0, stream>>>(bestd, out);
    } else {
        // Fallback: verified brute-force path (needs only 80 KB workspace).
        ull* keys = (ull*)d_ws;
        topk_kernel<<<dim3(BS * LUSED * SPLIT), dim3(NTHREADS), 0, stream>>>(preds, imgs, keys);
        finalize_kernel<<<dim3(1), dim3(NTHREADS), 0, stream>>>(preds, keys, out);
    }
}

// Round 3
// 111.646 us; speedup vs baseline: 1.8225x; 1.1049x over previous
//
#include <hip/hip_runtime.h>

#define IMG_SIZE 256
#define NPIX (IMG_SIZE * IMG_SIZE)
#define KSEL 5
#define BS 8
#define LL 64
#define LUSED 63          // row l=63's top-k is discarded by the roll — never compute it
#define NTHREADS 256
#define SPLIT 4           // (fallback path) blocks per (b,l) row
#define CHUNK (NPIX / SPLIT)
#define PBINS 256         // R-channel bins for the counting sort
#define NROWS (BS * LUSED)
#define NBPI 64           // sort blocks per image (1024 pixels each)
#define SENTK 0xFFFFFFFFFFFFFFFFULL

typedef unsigned long long ull;

// Branchless sorted-insert: loc[] ascending; bubble key in, evict the max.
__device__ __forceinline__ void sort_insert(ull loc[KSEL], ull key) {
    #pragma unroll
    for (int j = 0; j < KSEL; ++j) {
        const ull a = loc[j];
        const bool lt = key < a;
        loc[j] = lt ? key : a;
        key    = lt ? a : key;
    }
}

// Merge two ascending 5-lists, keep smallest 5 into a (fallback path only).
__device__ __forceinline__ void merge5(ull* a, const ull* b) {
    ull out[KSEL];
    int ia = 0, ib = 0;
    #pragma unroll
    for (int j = 0; j < KSEL; ++j) {
        const ull va = a[ia], vb = b[ib];
        const bool ta = va <= vb;
        out[j] = ta ? va : vb;
        ia += ta ? 1 : 0;
        ib += ta ? 0 : 1;
    }
    #pragma unroll
    for (int j = 0; j < KSEL; ++j) a[j] = out[j];
}

__device__ __forceinline__ ull
pix_key(float r0, float r1, float r2, float c0, float c1, float c2, int pix) {
    // Match numpy f32 exactly: no FMA contraction, ((d0^2+d1^2)+d2^2).
    float d0 = __fsub_rn(r0, c0);
    float d1 = __fsub_rn(r1, c1);
    float d2 = __fsub_rn(r2, c2);
    float s = __fadd_rn(__fadd_rn(__fmul_rn(d0, d0), __fmul_rn(d1, d1)), __fmul_rn(d2, d2));
    // s >= 0 -> uint bit order == float order; low bits = pixel index for
    // jax top_k's lower-index-first tie-break.
    return ((ull)__float_as_uint(s) << 32) | (unsigned int)pix;
}

// Binning formula — IDENTICAL in hist/scatter; consistent with rows_kernel's
// bin-edge prune (pixels in bin k have r within ~1ulp of [k/256,(k+1)/256),
// dominated by the 0.99/1e-12 slack).
__device__ __forceinline__ int rbin(float r) {
    return min(PBINS - 1, (int)(r * 256.0f));
}

// ---------------------------------------------------------------------------
// Fast path kernel 1: per-block histograms. 64 blocks/image, 1024 pixels each.
// ---------------------------------------------------------------------------
__global__ __launch_bounds__(NTHREADS)
void hist_kernel(const float* __restrict__ imgs,
                 unsigned* __restrict__ blockhist) {
    const int blk = blockIdx.x;           // 0 .. BS*NBPI-1
    const int img = blk >> 6;
    const int sub = blk & (NBPI - 1);
    const int t = threadIdx.x;
    __shared__ unsigned h[PBINS];
    h[t] = 0u;
    __syncthreads();
    const float4* rp = (const float4*)(imgs + (size_t)img * 3 * NPIX);
    const float4 r = rp[sub * NTHREADS + t];
    atomicAdd(&h[rbin(r.x)], 1u);
    atomicAdd(&h[rbin(r.y)], 1u);
    atomicAdd(&h[rbin(r.z)], 1u);
    atomicAdd(&h[rbin(r.w)], 1u);
    __syncthreads();
    blockhist[blk * PBINS + t] = h[t];
}

// ---------------------------------------------------------------------------
// Fast path kernel 2: per-image scan. One block/image, thread t = bin t.
// ---------------------------------------------------------------------------
__global__ __launch_bounds__(NTHREADS)
void scan_kernel(const unsigned* __restrict__ blockhist,
                 unsigned* __restrict__ bin_start,
                 unsigned* __restrict__ cur_base) {
    const int img = blockIdx.x;
    const int t = threadIdx.x;
    unsigned total = 0u;
    #pragma unroll 4
    for (int blk = 0; blk < NBPI; ++blk)
        total += blockhist[(img * NBPI + blk) * PBINS + t];

    __shared__ unsigned sc[PBINS];
    sc[t] = total;
    __syncthreads();
    for (int st = 1; st < PBINS; st <<= 1) {
        const unsigned v = (t >= st) ? sc[t - st] : 0u;
        __syncthreads();
        sc[t] += v;
        __syncthreads();
    }
    const unsigned start = sc[t] - total;     // exclusive prefix over bins
    bin_start[img * (PBINS + 1) + t] = start;
    if (t == 0) bin_start[img * (PBINS + 1) + PBINS] = NPIX;

    unsigned run = start;
    #pragma unroll 4
    for (int blk = 0; blk < NBPI; ++blk) {
        cur_base[(img * NBPI + blk) * PBINS + t] = run;
        run += blockhist[(img * NBPI + blk) * PBINS + t];
    }
}

// ---------------------------------------------------------------------------
// Fast path kernel 3: parallel scatter via per-block private reservations.
// Within-bin order nondeterministic (irrelevant: top-5 SET determined by
// unique (s,idx) keys; prune bound is order-independent).
// ---------------------------------------------------------------------------
__global__ __launch_bounds__(NTHREADS)
void scatter_kernel(const float* __restrict__ imgs,
                    const unsigned* __restrict__ cur_base,
                    float4* __restrict__ sorted) {
    const int blk = blockIdx.x;
    const int img = blk >> 6;
    const int sub = blk & (NBPI - 1);
    const int t = threadIdx.x;
    __shared__ unsigned cur[PBINS];
    cur[t] = cur_base[blk * PBINS + t];
    __syncthreads();

    const float* base = imgs + (size_t)img * 3 * NPIX;
    const int i4 = sub * NTHREADS + t;
    const float4 r  = ((const float4*)(base))[i4];
    const float4 g  = ((const float4*)(base + NPIX))[i4];
    const float4 bl = ((const float4*)(base + 2 * NPIX))[i4];
    float4* sp = sorted + (size_t)img * NPIX;
    const unsigned pix0 = (unsigned)(i4 * 4);

    unsigned p;
    p = atomicAdd(&cur[rbin(r.x)], 1u); sp[p] = make_float4(r.x, g.x, bl.x, __uint_as_float(pix0 + 0u));
    p = atomicAdd(&cur[rbin(r.y)], 1u); sp[p] = make_float4(r.y, g.y, bl.y, __uint_as_float(pix0 + 1u));
    p = atomicAdd(&cur[rbin(r.z)], 1u); sp[p] = make_float4(r.z, g.z, bl.z, __uint_as_float(pix0 + 2u));
    p = atomicAdd(&cur[rbin(r.w)], 1u); sp[p] = make_float4(r.w, g.w, bl.w, __uint_as_float(pix0 + 3u));
}

// ---------------------------------------------------------------------------
// Fast path kernel 4: ONE BLOCK (4 waves) per (b,l) row; super-step parallel
// bin expansion. Step 0: 4 nearest bins, one per wave, each wave building a
// wave-local top-5 (broadcast inserts keep it wave-uniform). LDS merge of the
// 4 local lists -> block-global top-5 (identical in every thread). Each later
// super-step prune-checks with the merged threshold (stale thr >= final s5 =>
// superset of bins => exact) and processes up to 4 more bins (2/side) in
// parallel. Every pixel evaluated exactly once with the verified pix_key, so
// the selected top-5 set is bit-identical to the serial version.
// ---------------------------------------------------------------------------
__global__ __launch_bounds__(NTHREADS)
void rows_kernel(const float* __restrict__ preds,
                 const float* __restrict__ imgs,
                 const float4* __restrict__ sorted,
                 const unsigned* __restrict__ bin_start,
                 float* __restrict__ bestd) {
    const int row = blockIdx.x;           // 0 .. NROWS-1
    const int wave = threadIdx.x >> 6;
    const int lane = threadIdx.x & 63;
    const int t = threadIdx.x;
    const int b = row / LUSED;
    const int l = row % LUSED;            // storage row; feeds loss row l+1

    __shared__ unsigned bst[PBINS + 1];
    __shared__ ull ml[4][KSEL];
    bst[t] = bin_start[b * (PBINS + 1) + t];
    if (t == 0) bst[PBINS] = NPIX;

    // Scrambled pooled indexing (verified): flat i = l*bs + b.
    const int i = l * BS + b;
    const int pb = i >> 6;
    const int pl = i & 63;
    const float px = preds[pb * (LL * 8) + pl * 8 + 0];
    const float py = preds[pb * (LL * 8) + pl * 8 + 1];

    const float cx = __fsub_rn(__fmul_rn(px, 256.0f), 0.5f);
    const float cy = __fsub_rn(__fmul_rn(py, 256.0f), 0.5f);
    const int ix = (int)rintf(cx);
    const int iy = (int)rintf(cy);
    const bool valid = (ix >= 0) && (ix < IMG_SIZE) && (iy >= 0) && (iy < IMG_SIZE);
    const int ixc = min(max(ix, 0), IMG_SIZE - 1);
    const int iyc = min(max(iy, 0), IMG_SIZE - 1);
    const float vmul = valid ? 1.0f : 0.0f;

    const float* imgb = imgs + (size_t)b * 3 * NPIX;
    const float c0 = imgb[0 * NPIX + iyc * IMG_SIZE + ixc] * vmul;
    const float c1 = imgb[1 * NPIX + iyc * IMG_SIZE + ixc] * vmul;
    const float c2 = imgb[2 * NPIX + iyc * IMG_SIZE + ixc] * vmul;

    const float4* sp = sorted + (size_t)b * NPIX;

    ull loc[KSEL];                        // block-global top-5 (uniform)
    #pragma unroll
    for (int j = 0; j < KSEL; ++j) loc[j] = SENTK;

    __syncthreads();                      // bst ready

    // Wave-cooperative: evaluate bin k, collecting candidates into wloc.
    // Re-ballot after each insert so inserts per 64-chunk stay ~O(5).
    auto process_bin = [&](int k, ull (&wloc)[KSEL]) {
        const int start = (int)bst[k];
        const int cnt = (int)bst[k + 1] - start;
        for (int o = lane; o < ((cnt + 63) & ~63); o += 64) {
            const bool act = o < cnt;
            const float4 v = sp[start + (act ? o : 0)];
            ull key = SENTK;
            if (act) key = pix_key(v.x, v.y, v.z, c0, c1, c2, (int)__float_as_uint(v.w));
            const ull gate = loc[KSEL - 1] < wloc[KSEL - 1] ? loc[KSEL - 1] : wloc[KSEL - 1];
            ull mask = __ballot(key < gate);
            while (mask) {
                const int ln = __ffsll(mask) - 1;
                mask &= mask - 1;
                const ull kk = __shfl(key, ln);   // broadcast; all lanes insert
                sort_insert(wloc, kk);
                mask &= __ballot(key < wloc[KSEL - 1]);
            }
        }
    };

    // Merge the 4 wave-local lists into every thread's global loc.
    auto merge_waves = [&](const ull (&wloc)[KSEL]) {
        if (lane == 0) {
            #pragma unroll
            for (int j = 0; j < KSEL; ++j) ml[wave][j] = wloc[j];
        }
        __syncthreads();
        #pragma unroll
        for (int w = 0; w < 4; ++w)
            #pragma unroll
            for (int j = 0; j < KSEL; ++j)
                sort_insert(loc, ml[w][j]);
        __syncthreads();
    };

    // Step 0: 4 nearest bins {bc, bc-1, bc+1, bc+2}, one per wave.
    const int bc = min(PBINS - 1, max(0, (int)(c0 * 256.0f)));
    {
        const int d = (wave == 1) ? -1 : (wave == 2) ? 1 : (wave == 3) ? 2 : 0;
        const int asg = bc + d;
        ull wl[KSEL];
        #pragma unroll
        for (int j = 0; j < KSEL; ++j) wl[j] = SENTK;
        if (asg >= 0 && asg < PBINS) process_bin(asg, wl);
        merge_waves(wl);
    }

    int lo = max(bc - 1, 0), hi = min(bc + 2, PBINS - 1);
    bool openL = (lo > 0), openR = (hi < PBINS - 1);
    while (openL || openR) {
        const unsigned thr = (unsigned)(loc[KSEL - 1] >> 32);  // f32 bits of s5 (or FFFF.. sentinel)
        int bins[4];
        int n = 0;
        // Up to 2 bins per side per super-step; prune with the (conservative,
        // stale-or-current) merged threshold. u32 cmp == f32 cmp (both >= 0);
        // sentinel thr is never exceeded -> never prunes.
        #pragma unroll
        for (int layer = 0; layer < 2; ++layer) {
            if (openL) {
                const float eL = __fsub_rn(c0, (float)lo * (1.0f / 256.0f));   // near edge of bin lo-1
                const float q = fmaxf(eL * eL * 0.99f - 1e-12f, 0.0f);
                if (__float_as_uint(q) > thr) openL = false;
                else { bins[n++] = lo - 1; lo -= 1; if (lo == 0) openL = false; }
            }
            if (openR) {
                const float eR = __fsub_rn((float)(hi + 1) * (1.0f / 256.0f), c0);
                const float q = fmaxf(eR * eR * 0.99f - 1e-12f, 0.0f);
                if (__float_as_uint(q) > thr) openR = false;
                else { bins[n++] = hi + 1; hi += 1; if (hi == PBINS - 1) openR = false; }
            }
        }
        if (n == 0) break;
        ull wl[KSEL];
        #pragma unroll
        for (int j = 0; j < KSEL; ++j) wl[j] = SENTK;
        if (wave < n) process_bin(bins[wave], wl);
        merge_waves(wl);
    }

    // Every thread holds the identical exact global top-5. Thread 0 computes
    // the loss element for loss row l+1 (same f32 ops as verified finalize).
    if (t == 0) {
        const float pxl = preds[b * (LL * 8) + (l + 1) * 8 + 0];
        const float pyl = preds[b * (LL * 8) + (l + 1) * 8 + 1];
        float best = 3.4028235e38f;
        #pragma unroll
        for (int k = 0; k < KSEL; ++k) {
            const int ixk = (int)(loc[k] & 0xFFFFFFFFULL);
            const float tx = (float)(ixk & 255) * (1.0f / 256.0f);
            const float ty = (float)(ixk >> 8) * (1.0f / 256.0f);
            const float dx = __fsub_rn(pxl, tx);
            const float dy = __fsub_rn(pyl, ty);
            const float dist = __fadd_rn(__fmul_rn(dx, dx), __fmul_rn(dy, dy));
            best = dist < best ? dist : best;
        }
        bestd[row] = best;
    }
}

// Fast path kernel 5: deterministic sum (bitwise-identical tree to the
// verified finalize tail).
__global__ __launch_bounds__(NTHREADS)
void sum_kernel(const float* __restrict__ bestd, float* __restrict__ out) {
    const int t = threadIdx.x;
    float acc = 0.0f;
    for (int p = t; p < NROWS; p += NTHREADS) acc += bestd[p];
    __shared__ float red[NTHREADS];
    red[t] = acc;
    __syncthreads();
    for (int s = NTHREADS / 2; s > 0; s >>= 1) {
        if (t < s) red[t] += red[t + s];
        __syncthreads();
    }
    if (t == 0) out[0] = red[0] / (float)(BS * (LL - 1));
}

// ---------------------------------------------------------------------------
// Fallback path (verified, 100.4 us): brute-force scan + merge. Used only if
// the workspace is too small for the sort buffers.
// ---------------------------------------------------------------------------
__global__ __launch_bounds__(NTHREADS)
void topk_kernel(const float* __restrict__ preds,
                 const float* __restrict__ imgs,
                 ull* __restrict__ keys_out) {
    const int blk = blockIdx.x;
    const int split = blk & (SPLIT - 1);
    const int row = blk / SPLIT;
    const int b = row / LUSED;
    const int l = row % LUSED;
    const int bid = b * LL + l;
    const int t = threadIdx.x;

    const int i = l * BS + b;
    const int pb = i >> 6;
    const int pl = i & 63;
    const float px = preds[pb * (LL * 8) + pl * 8 + 0];
    const float py = preds[pb * (LL * 8) + pl * 8 + 1];

    const float cx = __fsub_rn(__fmul_rn(px, 256.0f), 0.5f);
    const float cy = __fsub_rn(__fmul_rn(py, 256.0f), 0.5f);
    const int ix = (int)rintf(cx);
    const int iy = (int)rintf(cy);
    const bool valid = (ix >= 0) && (ix < IMG_SIZE) && (iy >= 0) && (iy < IMG_SIZE);
    const int ixc = min(max(ix, 0), IMG_SIZE - 1);
    const int iyc = min(max(iy, 0), IMG_SIZE - 1);
    const float vmul = valid ? 1.0f : 0.0f;

    const float* imgb = imgs + (size_t)b * 3 * NPIX;
    const float c0 = imgb[0 * NPIX + iyc * IMG_SIZE + ixc] * vmul;
    const float c1 = imgb[1 * NPIX + iyc * IMG_SIZE + ixc] * vmul;
    const float c2 = imgb[2 * NPIX + iyc * IMG_SIZE + ixc] * vmul;

    const float4* p0 = (const float4*)(imgb + 0 * NPIX);
    const float4* p1 = (const float4*)(imgb + 1 * NPIX);
    const float4* p2 = (const float4*)(imgb + 2 * NPIX);

    ull loc[KSEL];
    #pragma unroll
    for (int j = 0; j < KSEL; ++j) loc[j] = SENTK;

    const int v0 = split * (CHUNK / 4);
    #pragma unroll 2
    for (int it = 0; it < CHUNK / 4 / NTHREADS; ++it) {
        const int v = v0 + it * NTHREADS + t;
        float4 r0 = p0[v];
        float4 r1 = p1[v];
        float4 r2 = p2[v];
        const int base = v * 4;
        sort_insert(loc, pix_key(r0.x, r1.x, r2.x, c0, c1, c2, base + 0));
        sort_insert(loc, pix_key(r0.y, r1.y, r2.y, c0, c1, c2, base + 1));
        sort_insert(loc, pix_key(r0.z, r1.z, r2.z, c0, c1, c2, base + 2));
        sort_insert(loc, pix_key(r0.w, r1.w, r2.w, c0, c1, c2, base + 3));
    }

    __shared__ ull sk[NTHREADS * KSEL];
    #pragma unroll
    for (int j = 0; j < KSEL; ++j) sk[t * KSEL + j] = loc[j];
    __syncthreads();

    for (int s = NTHREADS / 2; s > 0; s >>= 1) {
        if (t < s) {
            ull a[KSEL], bb[KSEL];
            #pragma unroll
            for (int j = 0; j < KSEL; ++j) { a[j] = sk[t * KSEL + j]; bb[j] = sk[(t + s) * KSEL + j]; }
            merge5(a, bb);
            #pragma unroll
            for (int j = 0; j < KSEL; ++j) sk[t * KSEL + j] = a[j];
        }
        __syncthreads();
    }

    if (t < KSEL) {
        keys_out[((size_t)bid * SPLIT + split) * KSEL + t] = sk[t];
    }
}

__global__ __launch_bounds__(NTHREADS)
void finalize_kernel(const float* __restrict__ preds,
                     const ull* __restrict__ keys,
                     float* __restrict__ out) {
    const int t = threadIdx.x;
    float acc = 0.0f;

    for (int p = t; p < BS * LUSED; p += NTHREADS) {
        const int b = p / LUSED;
        const int l = p % LUSED + 1;
        const float px = preds[b * (LL * 8) + l * 8 + 0];
        const float py = preds[b * (LL * 8) + l * 8 + 1];

        const int srow = b * LL + (l - 1);
        ull loc[KSEL];
        #pragma unroll
        for (int j = 0; j < KSEL; ++j) loc[j] = SENTK;
        #pragma unroll
        for (int s = 0; s < SPLIT; ++s) {
            #pragma unroll
            for (int k = 0; k < KSEL; ++k) {
                sort_insert(loc, keys[((size_t)srow * SPLIT + s) * KSEL + k]);
            }
        }

        float best = 3.4028235e38f;
        #pragma unroll
        for (int k = 0; k < KSEL; ++k) {
            const int ixk = (int)(loc[k] & 0xFFFFFFFFULL);
            const float tx = (float)(ixk & 255) * (1.0f / 256.0f);
            const float ty = (float)(ixk >> 8) * (1.0f / 256.0f);
            const float dx = __fsub_rn(px, tx);
            const float dy = __fsub_rn(py, ty);
            const float dist = __fadd_rn(__fmul_rn(dx, dx), __fmul_rn(dy, dy));
            best = dist < best ? dist : best;
        }
        acc += best;
    }

    __shared__ float red[NTHREADS];
    red[t] = acc;
    __syncthreads();
    for (int s = NTHREADS / 2; s > 0; s >>= 1) {
        if (t < s) red[t] += red[t + s];
        __syncthreads();
    }
    if (t == 0) {
        out[0] = red[0] / (float)(BS * (LL - 1));
    }
}

extern "C" void kernel_launch(void* const* d_in, const int* in_sizes, int n_in,
                              void* d_out, int out_size, void* d_ws, size_t ws_size,
                              hipStream_t stream) {
    const float* preds = (const float*)d_in[0];   // (8, 64, 8) f32
    const float* imgs  = (const float*)d_in[1];   // (8, 3, 256, 256) f32
    float* out = (float*)d_out;                   // scalar f32

    const size_t SORT_BYTES   = (size_t)BS * NPIX * sizeof(float4);                       // 8 MB
    const size_t BSTART_BYTES = ((size_t)BS * (PBINS + 1) * sizeof(unsigned) + 15) & ~(size_t)15;
    const size_t BESTD_BYTES  = ((size_t)NROWS * sizeof(float) + 15) & ~(size_t)15;
    const size_t BHIST_BYTES  = (size_t)BS * NBPI * PBINS * sizeof(unsigned);             // 512 KB
    const size_t CBASE_BYTES  = (size_t)BS * NBPI * PBINS * sizeof(unsigned);             // 512 KB
    const size_t TOTAL = SORT_BYTES + BSTART_BYTES + BESTD_BYTES + BHIST_BYTES + CBASE_BYTES;

    if (ws_size >= TOTAL) {
        char* p = (char*)d_ws;
        float4*   sorted    = (float4*)p;              p += SORT_BYTES;
        unsigned* bin_start = (unsigned*)p;            p += BSTART_BYTES;
        float*    bestd     = (float*)p;               p += BESTD_BYTES;
        unsigned* blockhist = (unsigned*)p;            p += BHIST_BYTES;
        unsigned* cur_base  = (unsigned*)p;

        hist_kernel   <<<dim3(BS * NBPI), dim3(NTHREADS), 0, stream>>>(imgs, blockhist);
        scan_kernel   <<<dim3(BS),        dim3(NTHREADS), 0, stream>>>(blockhist, bin_start, cur_base);
        scatter_kernel<<<dim3(BS * NBPI), dim3(NTHREADS), 0, stream>>>(imgs, cur_base, sorted);
        rows_kernel   <<<dim3(NROWS),     dim3(NTHREADS), 0, stream>>>(preds, imgs, sorted, bin_start, bestd);
        sum_kernel    <<<dim3(1),         dim3(NTHREADS), 0, stream>>>(bestd, out);
    } else {
        // Fallback: verified brute-force path (needs only 80 KB workspace).
        ull* keys = (ull*)d_ws;
        topk_kernel<<<dim3(BS * LUSED * SPLIT), dim3(NTHREADS), 0, stream>>>(preds, imgs, keys);
        finalize_kernel<<<dim3(1), dim3(NTHREADS), 0, stream>>>(preds, keys, out);
    }
}